// Round 1
// 1421.006 us; speedup vs baseline: 2.6227x; 2.6227x over previous
//
#include <hip/hip_runtime.h>
#include <hip/hip_bf16.h>

typedef __hip_bfloat16 bf16;

#define NB 8
#define NS 1024
#define ND 512
#define NH 8
#define NDH 64
#define NDF 2048

__device__ __forceinline__ float tof(bf16 v) { return __bfloat162float(v); }
__device__ __forceinline__ float tof(float v) { return v; }
__device__ __forceinline__ void storev(float* p, float v) { *p = v; }
__device__ __forceinline__ void storev(bf16* p, float v) { *p = __float2bfloat16(v); }

// ---------------------------------------------------------------------------
// Generic tiled GEMM: C[M,N] = A[M,K] @ B[K,N] (+bias, +relu). f32 accumulate.
// BM=BN=64, BK=16, 256 threads, 4x4 micro-tile per thread.
// ---------------------------------------------------------------------------
template <typename AT, typename CT>
__global__ __launch_bounds__(256) void gemm_kernel(
    const AT* __restrict__ A, const float* __restrict__ Bw,
    const float* __restrict__ bias, CT* __restrict__ C,
    int M, int N, int K, int doRelu)
{
    __shared__ __align__(16) float As[16][65];  // [k][m], +1 pad: conflict-free stores
    __shared__ __align__(16) float Bs[16][64];  // [k][n], float4-readable
    const int row0 = blockIdx.y * 64;
    const int col0 = blockIdx.x * 64;
    const int tid = threadIdx.x;
    const int tx = tid & 15, ty = tid >> 4;

    float acc[4][4] = {};
    for (int k0 = 0; k0 < K; k0 += 16) {
#pragma unroll
        for (int l = 0; l < 4; ++l) {
            int idx = tid + l * 256;           // A tile 64x16
            int m = idx >> 4, kk = idx & 15;
            As[kk][m] = tof(A[(size_t)(row0 + m) * K + (k0 + kk)]);
        }
#pragma unroll
        for (int l = 0; l < 4; ++l) {
            int idx = tid + l * 256;           // B tile 16x64
            int kk = idx >> 6, n = idx & 63;
            Bs[kk][n] = Bw[(size_t)(k0 + kk) * N + (col0 + n)];
        }
        __syncthreads();
#pragma unroll
        for (int kk = 0; kk < 16; ++kk) {
            float a[4];
#pragma unroll
            for (int i = 0; i < 4; ++i) a[i] = As[kk][ty * 4 + i];
            float4 bv = *reinterpret_cast<const float4*>(&Bs[kk][tx * 4]);
            float b[4] = {bv.x, bv.y, bv.z, bv.w};
#pragma unroll
            for (int i = 0; i < 4; ++i)
#pragma unroll
                for (int j = 0; j < 4; ++j) acc[i][j] += a[i] * b[j];
        }
        __syncthreads();
    }
#pragma unroll
    for (int i = 0; i < 4; ++i) {
        int m = row0 + ty * 4 + i;
#pragma unroll
        for (int j = 0; j < 4; ++j) {
            int n = col0 + tx * 4 + j;
            float v = acc[i][j];
            if (bias) v += bias[n];
            if (doRelu) v = fmaxf(v, 0.0f);
            storev(&C[(size_t)m * N + n], v);
        }
    }
}

// ---------------------------------------------------------------------------
// Scores as two plain GEMMs over the causal/anti-causal tile triangles.
//   MODE 0: C[q,k] = (q+u_bias).K[k]          -> write raw into attn
//   MODE 1: C[q,u] = (q+v_bias).r[u]          -> attn[q, u-(S-1)+q] += C
// rel_shift identity: bd[q,k] = qv[q].r[k-q+S-1]; in (q,u) coords it is a
// plain GEMM, the shift is a per-row-contiguous offset applied at the write.
// 64x64 tile, 256 threads, 4x4 micro-tile, K=64 in one LDS stage.
// LDS = 2 * 64*65*4 B = 33 KiB -> 4 blocks/CU (16 waves/CU).
// ---------------------------------------------------------------------------
__device__ __forceinline__ int tri_decode_q(int tri) {
    int qt = (int)((sqrtf(8.0f * (float)tri + 1.0f) - 1.0f) * 0.5f);
    while ((qt + 1) * (qt + 2) / 2 <= tri) ++qt;
    while (qt * (qt + 1) / 2 > tri) --qt;
    return qt;
}

template <int MODE>
__global__ __launch_bounds__(256) void score_gemm_kernel(
    const float* __restrict__ qw, const float* __restrict__ kw,
    const float* __restrict__ rw, const float* __restrict__ ub,
    const float* __restrict__ vb, float* __restrict__ attn)
{
    __shared__ __align__(16) float As[64][65];  // [d][m]
    __shared__ __align__(16) float Bs[64][65];  // [d][n]
    const int tri = blockIdx.x % 136;           // 16*17/2 causal tiles
    const int bh = blockIdx.x / 136;
    const int h = bh & (NH - 1), b = bh >> 3;
    const int qt = tri_decode_q(tri);
    const int kt = tri - qt * (qt + 1) / 2;     // kt <= qt
    const int q0 = qt * 64;
    const int c0 = (MODE == 0) ? kt * 64 : (15 - kt) * 64;  // k0 or u0
    const int tid = threadIdx.x;
    const float* bias = (MODE == 0) ? ub : vb;

    // stage A: 64 q-rows x 64 d, transposed into As[d][m], bias added
#pragma unroll
    for (int l = 0; l < 4; ++l) {
        int idx = tid + l * 256;
        int m = idx >> 4, d4 = idx & 15;
        float4 a = *reinterpret_cast<const float4*>(
            qw + (size_t)(b * NS + q0 + m) * ND + h * NDH + d4 * 4);
        float4 bi = *reinterpret_cast<const float4*>(bias + h * NDH + d4 * 4);
        As[d4 * 4 + 0][m] = a.x + bi.x;
        As[d4 * 4 + 1][m] = a.y + bi.y;
        As[d4 * 4 + 2][m] = a.z + bi.z;
        As[d4 * 4 + 3][m] = a.w + bi.w;
    }
    // stage B: 64 rows (k or u) x 64 d, transposed into Bs[d][n]
#pragma unroll
    for (int l = 0; l < 4; ++l) {
        int idx = tid + l * 256;
        int n = idx >> 4, d4 = idx & 15;
        const float* src = (MODE == 0)
            ? kw + (size_t)(b * NS + c0 + n) * ND + h * NDH + d4 * 4
            : rw + (size_t)(c0 + n) * ND + h * NDH + d4 * 4;
        float4 v = *reinterpret_cast<const float4*>(src);
        Bs[d4 * 4 + 0][n] = v.x;
        Bs[d4 * 4 + 1][n] = v.y;
        Bs[d4 * 4 + 2][n] = v.z;
        Bs[d4 * 4 + 3][n] = v.w;
    }
    __syncthreads();

    const int tx = tid & 15, ty = tid >> 4;
    float acc[4][4] = {};
#pragma unroll 16
    for (int kk = 0; kk < 64; ++kk) {
        float a_[4], b_[4];
#pragma unroll
        for (int i = 0; i < 4; ++i) a_[i] = As[kk][ty * 4 + i];
#pragma unroll
        for (int j = 0; j < 4; ++j) b_[j] = Bs[kk][tx * 4 + j];
#pragma unroll
        for (int i = 0; i < 4; ++i)
#pragma unroll
            for (int j = 0; j < 4; ++j) acc[i][j] += a_[i] * b_[j];
    }

    if (MODE == 0) {
#pragma unroll
        for (int i = 0; i < 4; ++i) {
            int q = q0 + ty * 4 + i;
            float* rp = attn + ((size_t)(b * NH + h) * NS + q) * NS;
            float4 v = make_float4(acc[i][0], acc[i][1], acc[i][2], acc[i][3]);
            *reinterpret_cast<float4*>(rp + c0 + tx * 4) = v;  // k>q garbage: softmax ignores
        }
    } else {
#pragma unroll
        for (int i = 0; i < 4; ++i) {
            int q = q0 + ty * 4 + i;
            float* rp = attn + ((size_t)(b * NH + h) * NS + q) * NS;
#pragma unroll
            for (int j = 0; j < 4; ++j) {
                int u = c0 + tx * 4 + j;
                int k = u - (NS - 1) + q;       // always <= q; may be < 0
                if (k >= 0) rp[k] += acc[i][j];
            }
        }
    }
}

// ---------------------------------------------------------------------------
// Row softmax over attn (in place): scale 0.125, causal mask, zeros for k>q.
// One wave per row, row staged in LDS (4 KiB/wave).
// ---------------------------------------------------------------------------
__global__ __launch_bounds__(256) void softmax_kernel(float* __restrict__ attn)
{
    __shared__ float rows[4][NS];
    const int w = threadIdx.x >> 6, lane = threadIdx.x & 63;
    const int R = blockIdx.x * 4 + w;           // R = ((b*H+h)*S + q)
    const int q = R & (NS - 1);
    const int L = q + 1;
    float* ap = attn + (size_t)R * NS;

    float m = -1e30f;
    for (int kk = lane; kk < L; kk += 64) {
        float v = ap[kk] * 0.125f;
        rows[w][kk] = v;
        m = fmaxf(m, v);
    }
#pragma unroll
    for (int o = 32; o > 0; o >>= 1) m = fmaxf(m, __shfl_xor(m, o));
    float s = 0.f;
    for (int kk = lane; kk < L; kk += 64) {
        float e = __expf(rows[w][kk] - m);
        rows[w][kk] = e;
        s += e;
    }
#pragma unroll
    for (int o = 32; o > 0; o >>= 1) s += __shfl_xor(s, o);
    float inv = 1.0f / s;
    for (int kk = lane; kk < NS; kk += 64)
        ap[kk] = (kk < L) ? rows[w][kk] * inv : 0.0f;
}

// ---------------------------------------------------------------------------
// ctx[b,q,h,:] = sum_k attn[b,h,q,k] * v[b,k,h,:]   (causal K bound)
// One block = (b, h, 64 q-rows); BN = DH = 64, BK = 16.
// ---------------------------------------------------------------------------
__global__ __launch_bounds__(256) void pv_kernel(
    const float* __restrict__ attn, const bf16* __restrict__ vw,
    bf16* __restrict__ ctx)
{
    __shared__ __align__(16) float As[16][65];
    __shared__ __align__(16) float Bs[16][64];
    const int bid = blockIdx.x;
    const int qt = bid & 15;            // NS/64 = 16
    const int h = (bid >> 4) & (NH - 1);
    const int b = bid >> 7;
    const int q0 = qt * 64;
    const int tid = threadIdx.x;
    const int tx = tid & 15, ty = tid >> 4;

    const float* ap = attn + ((size_t)(b * NH + h) * NS + q0) * NS;
    float acc[4][4] = {};
    const int kmax = q0 + 64;  // attn is exactly 0 for k > q
    for (int k0 = 0; k0 < kmax; k0 += 16) {
#pragma unroll
        for (int l = 0; l < 4; ++l) {
            int idx = tid + l * 256;
            int m = idx >> 4, kk = idx & 15;
            As[kk][m] = ap[(size_t)m * NS + k0 + kk];
        }
#pragma unroll
        for (int l = 0; l < 4; ++l) {
            int idx = tid + l * 256;
            int kk = idx >> 6, n = idx & 63;
            Bs[kk][n] = tof(vw[((size_t)(b * NS + k0 + kk) * ND) + h * NDH + n]);
        }
        __syncthreads();
#pragma unroll
        for (int kk = 0; kk < 16; ++kk) {
            float a[4];
#pragma unroll
            for (int i = 0; i < 4; ++i) a[i] = As[kk][ty * 4 + i];
            float4 bv = *reinterpret_cast<const float4*>(&Bs[kk][tx * 4]);
            float bb[4] = {bv.x, bv.y, bv.z, bv.w};
#pragma unroll
            for (int i = 0; i < 4; ++i)
#pragma unroll
                for (int j = 0; j < 4; ++j) acc[i][j] += a[i] * bb[j];
        }
        __syncthreads();
    }
#pragma unroll
    for (int i = 0; i < 4; ++i) {
        int q = q0 + ty * 4 + i;
#pragma unroll
        for (int j = 0; j < 4; ++j) {
            int n = tx * 4 + j;
            ctx[((size_t)(b * NS + q) * ND) + h * NDH + n] = __float2bfloat16(acc[i][j]);
        }
    }
}

// ---------------------------------------------------------------------------
// out = LayerNorm(xin + yin) * g + b.  One block per row of 512.
// ---------------------------------------------------------------------------
template <typename T1, typename OT>
__global__ __launch_bounds__(256) void add_ln_kernel(
    const T1* __restrict__ xin, const float* __restrict__ yin,
    const float* __restrict__ g, const float* __restrict__ bb,
    OT* __restrict__ out)
{
    __shared__ float red[4];
    __shared__ float red2[4];
    const int row = blockIdx.x;
    const size_t base = (size_t)row * ND;
    const int tid = threadIdx.x;
    const int lane = tid & 63, w = tid >> 6;

    float v0 = tof(xin[base + tid]) + yin[base + tid];
    float v1 = tof(xin[base + tid + 256]) + yin[base + tid + 256];
    float s = v0 + v1;
#pragma unroll
    for (int o = 32; o > 0; o >>= 1) s += __shfl_xor(s, o);
    if (lane == 0) red[w] = s;
    __syncthreads();
    float mu = (red[0] + red[1] + red[2] + red[3]) * (1.0f / ND);
    float d0 = v0 - mu, d1 = v1 - mu;
    float vs = d0 * d0 + d1 * d1;
#pragma unroll
    for (int o = 32; o > 0; o >>= 1) vs += __shfl_xor(vs, o);
    if (lane == 0) red2[w] = vs;
    __syncthreads();
    float var = (red2[0] + red2[1] + red2[2] + red2[3]) * (1.0f / ND);
    float rs = rsqrtf(var + 1e-5f);
    storev(&out[base + tid], d0 * rs * g[tid] + bb[tid]);
    storev(&out[base + tid + 256], d1 * rs * g[tid + 256] + bb[tid + 256]);
}

// ---------------------------------------------------------------------------
extern "C" void kernel_launch(void* const* d_in, const int* in_sizes, int n_in,
                              void* d_out, int out_size, void* d_ws, size_t ws_size,
                              hipStream_t stream)
{
    // Inputs: float32 (mask bool, unused — causal pattern analytic).
    // Outputs: float32 (reference returns f32), compared after bf16 rounding.
    const float* x   = (const float*)d_in[0];
    const float* rel = (const float*)d_in[1];
    const float* Wq = (const float*)d_in[3];
    const float* Wk = (const float*)d_in[4];
    const float* Wv = (const float*)d_in[5];
    const float* Wr = (const float*)d_in[6];
    const float* Wo = (const float*)d_in[7];
    const float* ub = (const float*)d_in[8];
    const float* vb = (const float*)d_in[9];
    const float* g1 = (const float*)d_in[10];
    const float* be1 = (const float*)d_in[11];
    const float* W1 = (const float*)d_in[12];
    const float* bb1 = (const float*)d_in[13];
    const float* W2 = (const float*)d_in[14];
    const float* bb2 = (const float*)d_in[15];
    const float* g2 = (const float*)d_in[16];
    const float* be2 = (const float*)d_in[17];

    float* out0 = (float*)d_out;                 // (B,S,D) f32
    float* attn = out0 + (size_t)NB * NS * ND;   // (B,H,S,S) f32

    // workspace layout: f32 buffers first, then bf16
    char* ws = (char*)d_ws;
    const size_t needed = (size_t)16777216 * 4 + 2097152 + 8388608 * 2 + 33554432;
    if (ws_size < needed) return;
    float* tmp = (float*)ws; ws += (size_t)NB * NS * ND * 4;  // GEMM epilogue scratch
    float* h1  = (float*)ws; ws += (size_t)NB * NS * ND * 4;  // LN1 output
    float* qb  = (float*)ws; ws += (size_t)NB * NS * ND * 4;  // q (f32)
    float* kb  = (float*)ws; ws += (size_t)NB * NS * ND * 4;  // k (f32)
    float* rb  = (float*)ws; ws += (size_t)NS * ND * 4;       // r (f32)
    bf16* vbuf = (bf16*)ws;  ws += (size_t)NB * NS * ND * 2;  // v
    bf16* ctx  = (bf16*)ws;  ws += (size_t)NB * NS * ND * 2;  // attn @ v
    bf16* mid  = (bf16*)ws;  ws += (size_t)NB * NS * NDF * 2; // relu(h1@W1+b1)

    dim3 blk(256);
    const int M = NB * NS;

    gemm_kernel<float, float><<<dim3(ND / 64, M / 64), blk, 0, stream>>>(x, Wq, nullptr, qb, M, ND, ND, 0);
    gemm_kernel<float, float><<<dim3(ND / 64, M / 64), blk, 0, stream>>>(x, Wk, nullptr, kb, M, ND, ND, 0);
    gemm_kernel<float, bf16><<<dim3(ND / 64, M / 64), blk, 0, stream>>>(x, Wv, nullptr, vbuf, M, ND, ND, 0);
    gemm_kernel<float, float><<<dim3(ND / 64, NS / 64), blk, 0, stream>>>(rel, Wr, nullptr, rb, NS, ND, ND, 0);

    // scores: ac GEMM (causal tiles) -> attn raw; bd GEMM (shift at write, +=);
    // then per-row softmax (scale, mask, normalize, zero-fill).
    score_gemm_kernel<0><<<dim3(NB * NH * 136), blk, 0, stream>>>(qb, kb, rb, ub, vb, attn);
    score_gemm_kernel<1><<<dim3(NB * NH * 136), blk, 0, stream>>>(qb, kb, rb, ub, vb, attn);
    softmax_kernel<<<dim3(NB * NH * NS / 4), blk, 0, stream>>>(attn);

    pv_kernel<<<dim3(NB * NH * (NS / 64)), blk, 0, stream>>>(attn, vbuf, ctx);

    gemm_kernel<bf16, float><<<dim3(ND / 64, M / 64), blk, 0, stream>>>(ctx, Wo, nullptr, tmp, M, ND, ND, 0);
    add_ln_kernel<float, float><<<dim3(M), blk, 0, stream>>>(x, tmp, g1, be1, h1);

    gemm_kernel<float, bf16><<<dim3(NDF / 64, M / 64), blk, 0, stream>>>(h1, W1, bb1, mid, M, NDF, ND, 1);
    gemm_kernel<bf16, float><<<dim3(ND / 64, M / 64), blk, 0, stream>>>(mid, W2, bb2, tmp, M, ND, NDF, 0);
    add_ln_kernel<float, float><<<dim3(M), blk, 0, stream>>>(h1, tmp, g2, be2, out0);
}

// Round 2
// 674.216 us; speedup vs baseline: 5.5277x; 2.1076x over previous
//
#include <hip/hip_runtime.h>
#include <hip/hip_bf16.h>

typedef __hip_bfloat16 bf16;

#define NB 8
#define NS 1024
#define ND 512
#define NH 8
#define NDH 64
#define NDF 2048

typedef __attribute__((ext_vector_type(8))) short s16x8;
typedef __attribute__((ext_vector_type(4))) float f32x4;

__device__ __forceinline__ float tof(bf16 v) { return __bfloat162float(v); }
__device__ __forceinline__ float tof(float v) { return v; }
__device__ __forceinline__ void storev(float* p, float v) { *p = v; }
__device__ __forceinline__ void storev(bf16* p, float v) { *p = __float2bfloat16(v); }
__device__ __forceinline__ short f2bf(float f) {
    bf16 h = __float2bfloat16(f);
    return *reinterpret_cast<short*>(&h);
}

// ---------------------------------------------------------------------------
// cast f32 -> bf16 (bit-stored as short), 4 elems/thread
// ---------------------------------------------------------------------------
__global__ __launch_bounds__(256) void cast_kernel(
    const float4* __restrict__ in, short* __restrict__ out, int n4)
{
    int i = blockIdx.x * 256 + threadIdx.x;
    if (i < n4) {
        float4 v = in[i];
        short4 o;
        o.x = f2bf(v.x); o.y = f2bf(v.y); o.z = f2bf(v.z); o.w = f2bf(v.w);
        *reinterpret_cast<short4*>(out + (size_t)i * 4) = o;
    }
}

// ---------------------------------------------------------------------------
// W[K][N] f32 -> Wt[N][K] bf16.  32x32 tiles.
// ---------------------------------------------------------------------------
__global__ __launch_bounds__(256) void transpose_cast_kernel(
    const float* __restrict__ W, short* __restrict__ Wt, int K, int N)
{
    __shared__ float t[32][33];
    const int n0 = blockIdx.x * 32, k0 = blockIdx.y * 32;
    const int tx = threadIdx.x & 31, ty = threadIdx.x >> 5;  // 8 rows/pass
#pragma unroll
    for (int i = 0; i < 4; ++i)
        t[ty + i * 8][tx] = W[(size_t)(k0 + ty + i * 8) * N + n0 + tx];
    __syncthreads();
#pragma unroll
    for (int i = 0; i < 4; ++i)
        Wt[(size_t)(n0 + ty + i * 8) * K + k0 + tx] = f2bf(t[tx][ty + i * 8]);
}

// ---------------------------------------------------------------------------
// MFMA bf16 GEMM: C[M,N] = A[M,K] @ Bt[N,K]^T (+bias, +relu).
// A, Bt are bf16 (short bits), row-major with contiguous K.
// 128x128 tile, 256 threads = 4 waves (2x2), each wave 64x64 out,
// 4x4 fragments of v_mfma_f32_16x16x32_bf16. BK=32, single LDS stage.
// LDS rows padded to 40 shorts (80 B = 20 dwords): 16-lane fragment reads
// spread over 8 banks at 2-way (free), stores 16B-aligned.
// ---------------------------------------------------------------------------
template <typename CT>
__global__ __launch_bounds__(256) void mfma_gemm_kernel(
    const short* __restrict__ A, const short* __restrict__ Bt,
    const float* __restrict__ bias, CT* __restrict__ C,
    int M, int N, int K, int doRelu)
{
    __shared__ __align__(16) short As[128][40];
    __shared__ __align__(16) short Bs[128][40];
    const int row0 = blockIdx.y * 128;
    const int col0 = blockIdx.x * 128;
    const int tid = threadIdx.x;
    const int lane = tid & 63, w = tid >> 6;
    const int wm = w >> 1, wn = w & 1;
    const int lm = lane & 15, kq = lane >> 4;

    f32x4 acc[4][4] = {};

    for (int k0 = 0; k0 < K; k0 += 32) {
        // stage A,B tiles: 128 rows x 32 cols bf16 = 512 16B-chunks each
#pragma unroll
        for (int l = 0; l < 2; ++l) {
            int id = tid + l * 256;
            int r = id >> 2, ck = id & 3;
            *reinterpret_cast<s16x8*>(&As[r][ck * 8]) =
                *reinterpret_cast<const s16x8*>(A + (size_t)(row0 + r) * K + k0 + ck * 8);
            *reinterpret_cast<s16x8*>(&Bs[r][ck * 8]) =
                *reinterpret_cast<const s16x8*>(Bt + (size_t)(col0 + r) * K + k0 + ck * 8);
        }
        __syncthreads();

        s16x8 af[4], bfr[4];
#pragma unroll
        for (int i = 0; i < 4; ++i) {
            af[i]  = *reinterpret_cast<const s16x8*>(&As[wm * 64 + i * 16 + lm][kq * 8]);
            bfr[i] = *reinterpret_cast<const s16x8*>(&Bs[wn * 64 + i * 16 + lm][kq * 8]);
        }
#pragma unroll
        for (int i = 0; i < 4; ++i)
#pragma unroll
            for (int j = 0; j < 4; ++j)
                acc[i][j] = __builtin_amdgcn_mfma_f32_16x16x32_bf16(
                    af[i], bfr[j], acc[i][j], 0, 0, 0);
        __syncthreads();
    }

    // C/D layout (m89-verified): col = lane&15, row = (lane>>4)*4 + reg
#pragma unroll
    for (int i = 0; i < 4; ++i) {
        int cr0 = row0 + wm * 64 + i * 16 + kq * 4;
#pragma unroll
        for (int j = 0; j < 4; ++j) {
            int cc = col0 + wn * 64 + j * 16 + lm;
            float bv = bias ? bias[cc] : 0.0f;
#pragma unroll
            for (int r = 0; r < 4; ++r) {
                float v = acc[i][j][r] + bv;
                if (doRelu) v = fmaxf(v, 0.0f);
                storev(&C[(size_t)(cr0 + r) * N + cc], v);
            }
        }
    }
}

// ---------------------------------------------------------------------------
// Scores as two plain GEMMs over the causal tile triangle (f32 SIMT).
//   MODE 0: C[q,k] = (q+u_bias).K[k]          -> write raw into attn
//   MODE 1: C[q,u] = (q+v_bias).r[u]          -> attn[q, u-(S-1)+q] += C
// ---------------------------------------------------------------------------
__device__ __forceinline__ int tri_decode_q(int tri) {
    int qt = (int)((sqrtf(8.0f * (float)tri + 1.0f) - 1.0f) * 0.5f);
    while ((qt + 1) * (qt + 2) / 2 <= tri) ++qt;
    while (qt * (qt + 1) / 2 > tri) --qt;
    return qt;
}

template <int MODE>
__global__ __launch_bounds__(256) void score_gemm_kernel(
    const float* __restrict__ qw, const float* __restrict__ kw,
    const float* __restrict__ rw, const float* __restrict__ ub,
    const float* __restrict__ vb, float* __restrict__ attn)
{
    __shared__ __align__(16) float As[64][65];  // [d][m]
    __shared__ __align__(16) float Bs[64][65];  // [d][n]
    const int tri = blockIdx.x % 136;           // 16*17/2 causal tiles
    const int bh = blockIdx.x / 136;
    const int h = bh & (NH - 1), b = bh >> 3;
    const int qt = tri_decode_q(tri);
    const int kt = tri - qt * (qt + 1) / 2;     // kt <= qt
    const int q0 = qt * 64;
    const int c0 = (MODE == 0) ? kt * 64 : (15 - kt) * 64;  // k0 or u0
    const int tid = threadIdx.x;
    const float* bias = (MODE == 0) ? ub : vb;

#pragma unroll
    for (int l = 0; l < 4; ++l) {
        int idx = tid + l * 256;
        int m = idx >> 4, d4 = idx & 15;
        float4 a = *reinterpret_cast<const float4*>(
            qw + (size_t)(b * NS + q0 + m) * ND + h * NDH + d4 * 4);
        float4 bi = *reinterpret_cast<const float4*>(bias + h * NDH + d4 * 4);
        As[d4 * 4 + 0][m] = a.x + bi.x;
        As[d4 * 4 + 1][m] = a.y + bi.y;
        As[d4 * 4 + 2][m] = a.z + bi.z;
        As[d4 * 4 + 3][m] = a.w + bi.w;
    }
#pragma unroll
    for (int l = 0; l < 4; ++l) {
        int idx = tid + l * 256;
        int n = idx >> 4, d4 = idx & 15;
        const float* src = (MODE == 0)
            ? kw + (size_t)(b * NS + c0 + n) * ND + h * NDH + d4 * 4
            : rw + (size_t)(c0 + n) * ND + h * NDH + d4 * 4;
        float4 v = *reinterpret_cast<const float4*>(src);
        Bs[d4 * 4 + 0][n] = v.x;
        Bs[d4 * 4 + 1][n] = v.y;
        Bs[d4 * 4 + 2][n] = v.z;
        Bs[d4 * 4 + 3][n] = v.w;
    }
    __syncthreads();

    const int tx = tid & 15, ty = tid >> 4;
    float acc[4][4] = {};
#pragma unroll 16
    for (int kk = 0; kk < 64; ++kk) {
        float a_[4], b_[4];
#pragma unroll
        for (int i = 0; i < 4; ++i) a_[i] = As[kk][ty * 4 + i];
#pragma unroll
        for (int j = 0; j < 4; ++j) b_[j] = Bs[kk][tx * 4 + j];
#pragma unroll
        for (int i = 0; i < 4; ++i)
#pragma unroll
            for (int j = 0; j < 4; ++j) acc[i][j] += a_[i] * b_[j];
    }

    if (MODE == 0) {
#pragma unroll
        for (int i = 0; i < 4; ++i) {
            int q = q0 + ty * 4 + i;
            float* rp = attn + ((size_t)(b * NH + h) * NS + q) * NS;
            float4 v = make_float4(acc[i][0], acc[i][1], acc[i][2], acc[i][3]);
            *reinterpret_cast<float4*>(rp + c0 + tx * 4) = v;  // k>q garbage: softmax ignores
        }
    } else {
#pragma unroll
        for (int i = 0; i < 4; ++i) {
            int q = q0 + ty * 4 + i;
            float* rp = attn + ((size_t)(b * NH + h) * NS + q) * NS;
#pragma unroll
            for (int j = 0; j < 4; ++j) {
                int u = c0 + tx * 4 + j;
                int k = u - (NS - 1) + q;       // always <= q; may be < 0
                if (k >= 0) rp[k] += acc[i][j];
            }
        }
    }
}

// ---------------------------------------------------------------------------
// Row softmax over attn (in place): scale 0.125, causal mask, zeros for k>q.
// ---------------------------------------------------------------------------
__global__ __launch_bounds__(256) void softmax_kernel(float* __restrict__ attn)
{
    __shared__ float rows[4][NS];
    const int w = threadIdx.x >> 6, lane = threadIdx.x & 63;
    const int R = blockIdx.x * 4 + w;           // R = ((b*H+h)*S + q)
    const int q = R & (NS - 1);
    const int L = q + 1;
    float* ap = attn + (size_t)R * NS;

    float m = -1e30f;
    for (int kk = lane; kk < L; kk += 64) {
        float v = ap[kk] * 0.125f;
        rows[w][kk] = v;
        m = fmaxf(m, v);
    }
#pragma unroll
    for (int o = 32; o > 0; o >>= 1) m = fmaxf(m, __shfl_xor(m, o));
    float s = 0.f;
    for (int kk = lane; kk < L; kk += 64) {
        float e = __expf(rows[w][kk] - m);
        rows[w][kk] = e;
        s += e;
    }
#pragma unroll
    for (int o = 32; o > 0; o >>= 1) s += __shfl_xor(s, o);
    float inv = 1.0f / s;
    for (int kk = lane; kk < NS; kk += 64)
        ap[kk] = (kk < L) ? rows[w][kk] * inv : 0.0f;
}

// ---------------------------------------------------------------------------
// ctx[b,q,h,:] = sum_k attn[b,h,q,k] * v[b,k,h,:]   (causal K bound)
// ---------------------------------------------------------------------------
__global__ __launch_bounds__(256) void pv_kernel(
    const float* __restrict__ attn, const bf16* __restrict__ vw,
    bf16* __restrict__ ctx)
{
    __shared__ __align__(16) float As[16][65];
    __shared__ __align__(16) float Bs[16][64];
    const int bid = blockIdx.x;
    const int qt = bid & 15;            // NS/64 = 16
    const int h = (bid >> 4) & (NH - 1);
    const int b = bid >> 7;
    const int q0 = qt * 64;
    const int tid = threadIdx.x;
    const int tx = tid & 15, ty = tid >> 4;

    const float* ap = attn + ((size_t)(b * NH + h) * NS + q0) * NS;
    float acc[4][4] = {};
    const int kmax = q0 + 64;  // attn is exactly 0 for k > q
    for (int k0 = 0; k0 < kmax; k0 += 16) {
#pragma unroll
        for (int l = 0; l < 4; ++l) {
            int idx = tid + l * 256;
            int m = idx >> 4, kk = idx & 15;
            As[kk][m] = ap[(size_t)m * NS + k0 + kk];
        }
#pragma unroll
        for (int l = 0; l < 4; ++l) {
            int idx = tid + l * 256;
            int kk = idx >> 6, n = idx & 63;
            Bs[kk][n] = tof(vw[((size_t)(b * NS + k0 + kk) * ND) + h * NDH + n]);
        }
        __syncthreads();
#pragma unroll
        for (int kk = 0; kk < 16; ++kk) {
            float a[4];
#pragma unroll
            for (int i = 0; i < 4; ++i) a[i] = As[kk][ty * 4 + i];
            float4 bv = *reinterpret_cast<const float4*>(&Bs[kk][tx * 4]);
            float bb[4] = {bv.x, bv.y, bv.z, bv.w};
#pragma unroll
            for (int i = 0; i < 4; ++i)
#pragma unroll
                for (int j = 0; j < 4; ++j) acc[i][j] += a[i] * bb[j];
        }
        __syncthreads();
    }
#pragma unroll
    for (int i = 0; i < 4; ++i) {
        int q = q0 + ty * 4 + i;
#pragma unroll
        for (int j = 0; j < 4; ++j) {
            int n = tx * 4 + j;
            ctx[((size_t)(b * NS + q) * ND) + h * NDH + n] = __float2bfloat16(acc[i][j]);
        }
    }
}

// ---------------------------------------------------------------------------
// out = LayerNorm(xin + yin) * g + b.  Optional bf16 twin output.
// ---------------------------------------------------------------------------
__global__ __launch_bounds__(256) void add_ln_kernel(
    const float* __restrict__ xin, const float* __restrict__ yin,
    const float* __restrict__ g, const float* __restrict__ bb,
    float* __restrict__ out, short* __restrict__ out_bf)
{
    __shared__ float red[4];
    __shared__ float red2[4];
    const int row = blockIdx.x;
    const size_t base = (size_t)row * ND;
    const int tid = threadIdx.x;
    const int lane = tid & 63, w = tid >> 6;

    float v0 = xin[base + tid] + yin[base + tid];
    float v1 = xin[base + tid + 256] + yin[base + tid + 256];
    float s = v0 + v1;
#pragma unroll
    for (int o = 32; o > 0; o >>= 1) s += __shfl_xor(s, o);
    if (lane == 0) red[w] = s;
    __syncthreads();
    float mu = (red[0] + red[1] + red[2] + red[3]) * (1.0f / ND);
    float d0 = v0 - mu, d1 = v1 - mu;
    float vs = d0 * d0 + d1 * d1;
#pragma unroll
    for (int o = 32; o > 0; o >>= 1) vs += __shfl_xor(vs, o);
    if (lane == 0) red2[w] = vs;
    __syncthreads();
    float var = (red2[0] + red2[1] + red2[2] + red2[3]) * (1.0f / ND);
    float rs = rsqrtf(var + 1e-5f);
    float o0 = d0 * rs * g[tid] + bb[tid];
    float o1 = d1 * rs * g[tid + 256] + bb[tid + 256];
    out[base + tid] = o0;
    out[base + tid + 256] = o1;
    if (out_bf) {
        out_bf[base + tid] = f2bf(o0);
        out_bf[base + tid + 256] = f2bf(o1);
    }
}

// ---------------------------------------------------------------------------
extern "C" void kernel_launch(void* const* d_in, const int* in_sizes, int n_in,
                              void* d_out, int out_size, void* d_ws, size_t ws_size,
                              hipStream_t stream)
{
    const float* x   = (const float*)d_in[0];
    const float* rel = (const float*)d_in[1];
    const float* Wq = (const float*)d_in[3];
    const float* Wk = (const float*)d_in[4];
    const float* Wv = (const float*)d_in[5];
    const float* Wr = (const float*)d_in[6];
    const float* Wo = (const float*)d_in[7];
    const float* ub = (const float*)d_in[8];
    const float* vb = (const float*)d_in[9];
    const float* g1 = (const float*)d_in[10];
    const float* be1 = (const float*)d_in[11];
    const float* W1 = (const float*)d_in[12];
    const float* bb1 = (const float*)d_in[13];
    const float* W2 = (const float*)d_in[14];
    const float* bb2 = (const float*)d_in[15];
    const float* g2 = (const float*)d_in[16];
    const float* be2 = (const float*)d_in[17];

    float* out0 = (float*)d_out;                 // (B,S,D) f32
    float* attn = out0 + (size_t)NB * NS * ND;   // (B,H,S,S) f32

    // workspace layout
    char* ws = (char*)d_ws;
    const size_t SZ_QB  = (size_t)NB * NS * ND * 4;    // 16 MB
    const size_t SZ_RB  = (size_t)NS * ND * 4;         // 2 MB
    const size_t SZ_BF  = (size_t)NB * NS * ND * 2;    // 8 MB
    const size_t SZ_MID = (size_t)NB * NS * NDF * 2;   // 32 MB
    const size_t SZ_RBF = (size_t)NS * ND * 2;         // 1 MB
    const size_t SZ_W   = (size_t)ND * ND * 2;         // 512 KB
    const size_t SZ_W12 = (size_t)ND * NDF * 2;        // 2 MB
    const size_t needed = 2 * SZ_QB + SZ_RB + 4 * SZ_BF + SZ_MID + SZ_RBF + 5 * SZ_W + 2 * SZ_W12;
    if (ws_size < needed) return;

    float* qb   = (float*)ws; ws += SZ_QB;   // q (f32); later reused as GEMM scratch "tmp"
    float* kb   = (float*)ws; ws += SZ_QB;   // k (f32); later reused as h1
    float* rb   = (float*)ws; ws += SZ_RB;   // r (f32)
    short* x_bf = (short*)ws; ws += SZ_BF;   // x cast to bf16
    short* vbuf = (short*)ws; ws += SZ_BF;   // v (bf16)
    short* ctx  = (short*)ws; ws += SZ_BF;   // attn @ v (bf16)
    short* h1b  = (short*)ws; ws += SZ_BF;   // h1 cast to bf16
    short* mid  = (short*)ws; ws += SZ_MID;  // relu(h1@W1+b1) (bf16)
    short* rel_bf = (short*)ws; ws += SZ_RBF;
    short* WqT = (short*)ws; ws += SZ_W;
    short* WkT = (short*)ws; ws += SZ_W;
    short* WvT = (short*)ws; ws += SZ_W;
    short* WrT = (short*)ws; ws += SZ_W;
    short* WoT = (short*)ws; ws += SZ_W;
    short* W1T = (short*)ws; ws += SZ_W12;   // (NDF, ND)
    short* W2T = (short*)ws; ws += SZ_W12;   // (ND, NDF)
    float* tmp = qb;   // alias: qb dead after score kernels
    float* h1  = kb;   // alias: kb dead after score kernels

    dim3 blk(256);
    const int M = NB * NS;

    // casts + weight transposes (bf16)
    cast_kernel<<<dim3((M * ND / 4 + 255) / 256), blk, 0, stream>>>((const float4*)x, x_bf, M * ND / 4);
    cast_kernel<<<dim3((NS * ND / 4 + 255) / 256), blk, 0, stream>>>((const float4*)rel, rel_bf, NS * ND / 4);
    transpose_cast_kernel<<<dim3(ND / 32, ND / 32), blk, 0, stream>>>(Wq, WqT, ND, ND);
    transpose_cast_kernel<<<dim3(ND / 32, ND / 32), blk, 0, stream>>>(Wk, WkT, ND, ND);
    transpose_cast_kernel<<<dim3(ND / 32, ND / 32), blk, 0, stream>>>(Wv, WvT, ND, ND);
    transpose_cast_kernel<<<dim3(ND / 32, ND / 32), blk, 0, stream>>>(Wr, WrT, ND, ND);
    transpose_cast_kernel<<<dim3(ND / 32, ND / 32), blk, 0, stream>>>(Wo, WoT, ND, ND);
    transpose_cast_kernel<<<dim3(NDF / 32, ND / 32), blk, 0, stream>>>(W1, W1T, ND, NDF);
    transpose_cast_kernel<<<dim3(ND / 32, NDF / 32), blk, 0, stream>>>(W2, W2T, NDF, ND);

    // projections (MFMA)
    mfma_gemm_kernel<float><<<dim3(ND / 128, M / 128), blk, 0, stream>>>(x_bf, WqT, nullptr, qb, M, ND, ND, 0);
    mfma_gemm_kernel<float><<<dim3(ND / 128, M / 128), blk, 0, stream>>>(x_bf, WkT, nullptr, kb, M, ND, ND, 0);
    mfma_gemm_kernel<bf16 ><<<dim3(ND / 128, M / 128), blk, 0, stream>>>(x_bf, WvT, nullptr, (bf16*)vbuf, M, ND, ND, 0);
    mfma_gemm_kernel<float><<<dim3(ND / 128, NS / 128), blk, 0, stream>>>(rel_bf, WrT, nullptr, rb, NS, ND, ND, 0);

    // scores: ac GEMM -> attn raw; bd GEMM (shift at write, +=); softmax.
    score_gemm_kernel<0><<<dim3(NB * NH * 136), blk, 0, stream>>>(qb, kb, rb, ub, vb, attn);
    score_gemm_kernel<1><<<dim3(NB * NH * 136), blk, 0, stream>>>(qb, kb, rb, ub, vb, attn);
    softmax_kernel<<<dim3(NB * NH * NS / 4), blk, 0, stream>>>(attn);

    pv_kernel<<<dim3(NB * NH * (NS / 64)), blk, 0, stream>>>(attn, (const bf16*)vbuf, (bf16*)ctx);

    // output proj + LN1 (h1 f32 + bf16 twin)
    mfma_gemm_kernel<float><<<dim3(ND / 128, M / 128), blk, 0, stream>>>(ctx, WoT, nullptr, tmp, M, ND, ND, 0);
    add_ln_kernel<<<dim3(M), blk, 0, stream>>>(x, tmp, g1, be1, h1, h1b);

    // FFN (MFMA) + LN2
    mfma_gemm_kernel<bf16 ><<<dim3(NDF / 128, M / 128), blk, 0, stream>>>(h1b, W1T, bb1, (bf16*)mid, M, NDF, ND, 1);
    mfma_gemm_kernel<float><<<dim3(ND / 128, M / 128), blk, 0, stream>>>(mid, W2T, bb2, tmp, M, ND, NDF, 0);
    add_ln_kernel<<<dim3(M), blk, 0, stream>>>(h1, tmp, g2, be2, out0, nullptr);
}

// Round 3
// 500.378 us; speedup vs baseline: 7.4481x; 1.3474x over previous
//
#include <hip/hip_runtime.h>
#include <hip/hip_bf16.h>

typedef __hip_bfloat16 bf16;

#define NB 8
#define NS 1024
#define ND 512
#define NH 8
#define NDH 64
#define NDF 2048

typedef __attribute__((ext_vector_type(8))) short s16x8;
typedef __attribute__((ext_vector_type(4))) float f32x4;

__device__ __forceinline__ void storev(float* p, float v) { *p = v; }
__device__ __forceinline__ void storev(bf16* p, float v) { *p = __float2bfloat16(v); }
__device__ __forceinline__ short f2bf(float f) {
    bf16 h = __float2bfloat16(f);
    return *reinterpret_cast<short*>(&h);
}

// ---------------------------------------------------------------------------
// cast f32 -> bf16 (bit-stored as short), 4 elems/thread
// ---------------------------------------------------------------------------
__global__ __launch_bounds__(256) void cast_kernel(
    const float4* __restrict__ in, short* __restrict__ out, int n4)
{
    int i = blockIdx.x * 256 + threadIdx.x;
    if (i < n4) {
        float4 v = in[i];
        short4 o;
        o.x = f2bf(v.x); o.y = f2bf(v.y); o.z = f2bf(v.z); o.w = f2bf(v.w);
        *reinterpret_cast<short4*>(out + (size_t)i * 4) = o;
    }
}

// ---------------------------------------------------------------------------
// W[K][N] f32 -> Wt[N][K] bf16.  32x32 tiles.
// ---------------------------------------------------------------------------
__global__ __launch_bounds__(256) void transpose_cast_kernel(
    const float* __restrict__ W, short* __restrict__ Wt, int K, int N)
{
    __shared__ float t[32][33];
    const int n0 = blockIdx.x * 32, k0 = blockIdx.y * 32;
    const int tx = threadIdx.x & 31, ty = threadIdx.x >> 5;  // 8 rows/pass
#pragma unroll
    for (int i = 0; i < 4; ++i)
        t[ty + i * 8][tx] = W[(size_t)(k0 + ty + i * 8) * N + n0 + tx];
    __syncthreads();
#pragma unroll
    for (int i = 0; i < 4; ++i)
        Wt[(size_t)(n0 + ty + i * 8) * K + k0 + tx] = f2bf(t[tx][ty + i * 8]);
}

// ---------------------------------------------------------------------------
// v[b,s,h,n] bf16 -> vT[b,h,n,s] bf16.  32x32 tiles per (b,h).
// ---------------------------------------------------------------------------
__global__ __launch_bounds__(256) void transpose_v_kernel(
    const short* __restrict__ v, short* __restrict__ vT)
{
    __shared__ short t[32][33];
    const int s0 = blockIdx.x * 32, n0 = blockIdx.y * 32;
    const int bh = blockIdx.z;
    const int h = bh & (NH - 1), b = bh >> 3;
    const int tx = threadIdx.x & 31, ty = threadIdx.x >> 5;
#pragma unroll
    for (int i = 0; i < 4; ++i)
        t[ty + i * 8][tx] = v[(size_t)(b * NS + s0 + ty + i * 8) * ND + h * NDH + n0 + tx];
    __syncthreads();
#pragma unroll
    for (int i = 0; i < 4; ++i)
        vT[((size_t)bh * NDH + n0 + ty + i * 8) * NS + s0 + tx] = t[tx][ty + i * 8];
}

// ---------------------------------------------------------------------------
// MFMA bf16 GEMM: C[M,N] = A[M,K] @ Bt[N,K]^T (+bias, +relu).
// Optional dual epilogue: C2 = bf16(acc + bias2) (for qu/qv split).
// 128x128 tile, 4 waves (2x2), 4x4 fragments of 16x16x32, BK=32.
// ---------------------------------------------------------------------------
template <typename CT>
__global__ __launch_bounds__(256) void mfma_gemm_kernel(
    const short* __restrict__ A, const short* __restrict__ Bt,
    const float* __restrict__ bias, CT* __restrict__ C,
    const float* __restrict__ bias2, short* __restrict__ C2,
    int M, int N, int K, int doRelu)
{
    __shared__ __align__(16) short As[128][40];
    __shared__ __align__(16) short Bs[128][40];
    const int row0 = blockIdx.y * 128;
    const int col0 = blockIdx.x * 128;
    const int tid = threadIdx.x;
    const int lane = tid & 63, w = tid >> 6;
    const int wm = w >> 1, wn = w & 1;
    const int lm = lane & 15, kq = lane >> 4;

    f32x4 acc[4][4] = {};

    for (int k0 = 0; k0 < K; k0 += 32) {
#pragma unroll
        for (int l = 0; l < 2; ++l) {
            int id = tid + l * 256;
            int r = id >> 2, ck = id & 3;
            *reinterpret_cast<s16x8*>(&As[r][ck * 8]) =
                *reinterpret_cast<const s16x8*>(A + (size_t)(row0 + r) * K + k0 + ck * 8);
            *reinterpret_cast<s16x8*>(&Bs[r][ck * 8]) =
                *reinterpret_cast<const s16x8*>(Bt + (size_t)(col0 + r) * K + k0 + ck * 8);
        }
        __syncthreads();

        s16x8 af[4], bfr[4];
#pragma unroll
        for (int i = 0; i < 4; ++i) {
            af[i]  = *reinterpret_cast<const s16x8*>(&As[wm * 64 + i * 16 + lm][kq * 8]);
            bfr[i] = *reinterpret_cast<const s16x8*>(&Bs[wn * 64 + i * 16 + lm][kq * 8]);
        }
#pragma unroll
        for (int i = 0; i < 4; ++i)
#pragma unroll
            for (int j = 0; j < 4; ++j)
                acc[i][j] = __builtin_amdgcn_mfma_f32_16x16x32_bf16(
                    af[i], bfr[j], acc[i][j], 0, 0, 0);
        __syncthreads();
    }

    // C/D layout: col = lane&15, row = (lane>>4)*4 + reg
#pragma unroll
    for (int i = 0; i < 4; ++i) {
        int cr0 = row0 + wm * 64 + i * 16 + kq * 4;
#pragma unroll
        for (int j = 0; j < 4; ++j) {
            int cc = col0 + wn * 64 + j * 16 + lm;
            float bv = bias ? bias[cc] : 0.0f;
            float bv2 = bias2 ? bias2[cc] : 0.0f;
#pragma unroll
            for (int r = 0; r < 4; ++r) {
                float v = acc[i][j][r] + bv;
                if (doRelu) v = fmaxf(v, 0.0f);
                storev(&C[(size_t)(cr0 + r) * N + cc], v);
                if (C2) C2[(size_t)(cr0 + r) * N + cc] = f2bf(acc[i][j][r] + bv2);
            }
        }
    }
}

// ---------------------------------------------------------------------------
// Score GEMMs on MFMA over 128x128 tile triangles. K = 64 (single stage).
//   MODE 0: attn_raw[q,k] = qu[q].k[k]    over causal tiles (kt <= qt)
//   MODE 1: bdbuf[q,u]    = qv[q].r[u]    over anti tiles   (qt+ut >= 7)
// rel_shift: bd[q,k] = bdbuf[q, k + S-1-q] -- contiguous slice per row,
// applied at softmax read. Diagonal-tile garbage is never read.
// ---------------------------------------------------------------------------
__device__ __forceinline__ int tri_decode_q(int tri) {
    int qt = (int)((sqrtf(8.0f * (float)tri + 1.0f) - 1.0f) * 0.5f);
    while ((qt + 1) * (qt + 2) / 2 <= tri) ++qt;
    while (qt * (qt + 1) / 2 > tri) --qt;
    return qt;
}

template <int MODE>
__global__ __launch_bounds__(256) void score_mfma_kernel(
    const short* __restrict__ qu, const short* __restrict__ qv,
    const short* __restrict__ kb, const short* __restrict__ rb,
    float* __restrict__ attn, float* __restrict__ bdbuf)
{
    __shared__ __align__(16) short As[128][72];
    __shared__ __align__(16) short Bs[128][72];
    const int tri = blockIdx.x % 36;            // 8*9/2 tiles of 128
    const int bh  = blockIdx.x / 36;
    const int h = bh & (NH - 1), b = bh >> 3;
    const int qt = tri_decode_q(tri);
    const int jt = tri - qt * (qt + 1) / 2;     // jt <= qt
    const int q0 = qt * 128;
    const int c0 = (MODE == 0) ? jt * 128 : (7 - qt + jt) * 128;  // k0 or u0
    const int tid = threadIdx.x;
    const short* Asrc = (MODE == 0) ? qu : qv;

#pragma unroll
    for (int l = 0; l < 4; ++l) {
        int idx = tid + l * 256;
        int r = idx >> 3, c = idx & 7;
        *reinterpret_cast<s16x8*>(&As[r][c * 8]) =
            *reinterpret_cast<const s16x8*>(Asrc + (size_t)(b * NS + q0 + r) * ND + h * NDH + c * 8);
        const short* bsrc = (MODE == 0)
            ? kb + (size_t)(b * NS + c0 + r) * ND + h * NDH + c * 8
            : rb + (size_t)(c0 + r) * ND + h * NDH + c * 8;
        *reinterpret_cast<s16x8*>(&Bs[r][c * 8]) = *reinterpret_cast<const s16x8*>(bsrc);
    }
    __syncthreads();

    const int lane = tid & 63, w = tid >> 6;
    const int wm = w >> 1, wn = w & 1;
    const int lm = lane & 15, kq = lane >> 4;
    f32x4 acc[4][4] = {};
#pragma unroll
    for (int ks = 0; ks < 2; ++ks) {
        s16x8 af[4], bfr[4];
#pragma unroll
        for (int i = 0; i < 4; ++i) {
            af[i]  = *reinterpret_cast<const s16x8*>(&As[wm * 64 + i * 16 + lm][ks * 32 + kq * 8]);
            bfr[i] = *reinterpret_cast<const s16x8*>(&Bs[wn * 64 + i * 16 + lm][ks * 32 + kq * 8]);
        }
#pragma unroll
        for (int i = 0; i < 4; ++i)
#pragma unroll
            for (int j = 0; j < 4; ++j)
                acc[i][j] = __builtin_amdgcn_mfma_f32_16x16x32_bf16(
                    af[i], bfr[j], acc[i][j], 0, 0, 0);
    }

    float* outp = (MODE == 0) ? attn : bdbuf;
#pragma unroll
    for (int i = 0; i < 4; ++i) {
        int rr0 = q0 + wm * 64 + i * 16 + kq * 4;
#pragma unroll
        for (int j = 0; j < 4; ++j) {
            int cc = c0 + wn * 64 + j * 16 + lm;
#pragma unroll
            for (int r = 0; r < 4; ++r)
                outp[((size_t)bh * NS + rr0 + r) * NS + cc] = acc[i][j][r];
        }
    }
}

// ---------------------------------------------------------------------------
// Row softmax: val = (ac[q,k] + bd[q, k+S-1-q]) * 0.125, causal, normalize.
// Writes attn in place (exact zeros for k > q).
// ---------------------------------------------------------------------------
__global__ __launch_bounds__(256) void softmax_kernel(
    float* __restrict__ attn, const float* __restrict__ bdbuf)
{
    __shared__ float rows[4][NS];
    const int w = threadIdx.x >> 6, lane = threadIdx.x & 63;
    const int R = blockIdx.x * 4 + w;           // R = ((b*H+h)*S + q)
    const int q = R & (NS - 1);
    const int L = q + 1;
    float* ap = attn + (size_t)R * NS;
    const float* bp = bdbuf + (size_t)R * NS + (NS - 1 - q);

    float m = -1e30f;
    for (int kk = lane; kk < L; kk += 64) {
        float v = (ap[kk] + bp[kk]) * 0.125f;
        rows[w][kk] = v;
        m = fmaxf(m, v);
    }
#pragma unroll
    for (int o = 32; o > 0; o >>= 1) m = fmaxf(m, __shfl_xor(m, o));
    float s = 0.f;
    for (int kk = lane; kk < L; kk += 64) {
        float e = __expf(rows[w][kk] - m);
        rows[w][kk] = e;
        s += e;
    }
#pragma unroll
    for (int o = 32; o > 0; o >>= 1) s += __shfl_xor(s, o);
    float inv = 1.0f / s;
    for (int kk = lane; kk < NS; kk += 64)
        ap[kk] = (kk < L) ? rows[w][kk] * inv : 0.0f;
}

// ---------------------------------------------------------------------------
// PV on MFMA: ctx[b,q,h,:] = sum_k attn[b,h,q,k] * v[b,k,h,:].
// Block = (b,h,64 q-rows), A = attn (f32 -> bf16 in staging), B = vT rows.
// 4 waves (2x2), wave tile 32x32, 2x2 fragments, BK=32, causal K bound.
// ---------------------------------------------------------------------------
__global__ __launch_bounds__(256) void pv_mfma_kernel(
    const float* __restrict__ attn, const short* __restrict__ vT,
    short* __restrict__ ctx)
{
    __shared__ __align__(16) short As[64][40];
    __shared__ __align__(16) short Bs[64][40];
    const int bid = blockIdx.x;
    const int qp = bid & 15;
    const int bh = bid >> 4;
    const int h = bh & (NH - 1), b = bh >> 3;
    const int q0 = qp * 64;
    const int tid = threadIdx.x;
    const int lane = tid & 63, w = tid >> 6;
    const int wm = w >> 1, wn = w & 1;
    const int lm = lane & 15, kq = lane >> 4;

    f32x4 acc[2][2] = {};
    const int kmax = q0 + 64;   // attn is exactly 0 for k > q
    for (int k0 = 0; k0 < kmax; k0 += 32) {
#pragma unroll
        for (int l = 0; l < 2; ++l) {
            int idx = tid + l * 256;
            int r = idx >> 3, c4 = idx & 7;
            float4 v = *reinterpret_cast<const float4*>(
                attn + ((size_t)bh * NS + q0 + r) * NS + k0 + c4 * 4);
            short4 o;
            o.x = f2bf(v.x); o.y = f2bf(v.y); o.z = f2bf(v.z); o.w = f2bf(v.w);
            *reinterpret_cast<short4*>(&As[r][c4 * 4]) = o;
        }
        {
            int r = tid >> 2, c = tid & 3;
            *reinterpret_cast<s16x8*>(&Bs[r][c * 8]) =
                *reinterpret_cast<const s16x8*>(vT + ((size_t)bh * NDH + r) * NS + k0 + c * 8);
        }
        __syncthreads();

        s16x8 af[2], bfr[2];
#pragma unroll
        for (int i = 0; i < 2; ++i) {
            af[i]  = *reinterpret_cast<const s16x8*>(&As[wm * 32 + i * 16 + lm][kq * 8]);
            bfr[i] = *reinterpret_cast<const s16x8*>(&Bs[wn * 32 + i * 16 + lm][kq * 8]);
        }
#pragma unroll
        for (int i = 0; i < 2; ++i)
#pragma unroll
            for (int j = 0; j < 2; ++j)
                acc[i][j] = __builtin_amdgcn_mfma_f32_16x16x32_bf16(
                    af[i], bfr[j], acc[i][j], 0, 0, 0);
        __syncthreads();
    }

#pragma unroll
    for (int i = 0; i < 2; ++i) {
        int q = q0 + wm * 32 + i * 16 + kq * 4;
#pragma unroll
        for (int j = 0; j < 2; ++j) {
            int n = wn * 32 + j * 16 + lm;
#pragma unroll
            for (int r = 0; r < 4; ++r)
                ctx[(size_t)(b * NS + q + r) * ND + h * NDH + n] = f2bf(acc[i][j][r]);
        }
    }
}

// ---------------------------------------------------------------------------
// out = LayerNorm(xin + yin) * g + b.  Optional bf16 twin output.
// ---------------------------------------------------------------------------
__global__ __launch_bounds__(256) void add_ln_kernel(
    const float* __restrict__ xin, const float* __restrict__ yin,
    const float* __restrict__ g, const float* __restrict__ bb,
    float* __restrict__ out, short* __restrict__ out_bf)
{
    __shared__ float red[4];
    __shared__ float red2[4];
    const int row = blockIdx.x;
    const size_t base = (size_t)row * ND;
    const int tid = threadIdx.x;
    const int lane = tid & 63, w = tid >> 6;

    float v0 = xin[base + tid] + yin[base + tid];
    float v1 = xin[base + tid + 256] + yin[base + tid + 256];
    float s = v0 + v1;
#pragma unroll
    for (int o = 32; o > 0; o >>= 1) s += __shfl_xor(s, o);
    if (lane == 0) red[w] = s;
    __syncthreads();
    float mu = (red[0] + red[1] + red[2] + red[3]) * (1.0f / ND);
    float d0 = v0 - mu, d1 = v1 - mu;
    float vs = d0 * d0 + d1 * d1;
#pragma unroll
    for (int o = 32; o > 0; o >>= 1) vs += __shfl_xor(vs, o);
    if (lane == 0) red2[w] = vs;
    __syncthreads();
    float var = (red2[0] + red2[1] + red2[2] + red2[3]) * (1.0f / ND);
    float rs = rsqrtf(var + 1e-5f);
    float o0 = d0 * rs * g[tid] + bb[tid];
    float o1 = d1 * rs * g[tid + 256] + bb[tid + 256];
    out[base + tid] = o0;
    out[base + tid + 256] = o1;
    if (out_bf) {
        out_bf[base + tid] = f2bf(o0);
        out_bf[base + tid + 256] = f2bf(o1);
    }
}

// ---------------------------------------------------------------------------
extern "C" void kernel_launch(void* const* d_in, const int* in_sizes, int n_in,
                              void* d_out, int out_size, void* d_ws, size_t ws_size,
                              hipStream_t stream)
{
    const float* x   = (const float*)d_in[0];
    const float* rel = (const float*)d_in[1];
    const float* Wq = (const float*)d_in[3];
    const float* Wk = (const float*)d_in[4];
    const float* Wv = (const float*)d_in[5];
    const float* Wr = (const float*)d_in[6];
    const float* Wo = (const float*)d_in[7];
    const float* ub = (const float*)d_in[8];
    const float* vb = (const float*)d_in[9];
    const float* g1 = (const float*)d_in[10];
    const float* be1 = (const float*)d_in[11];
    const float* W1 = (const float*)d_in[12];
    const float* bb1 = (const float*)d_in[13];
    const float* W2 = (const float*)d_in[14];
    const float* bb2 = (const float*)d_in[15];
    const float* g2 = (const float*)d_in[16];
    const float* be2 = (const float*)d_in[17];

    float* out0 = (float*)d_out;                 // (B,S,D) f32
    float* attn = out0 + (size_t)NB * NS * ND;   // (B,H,S,S) f32

    // workspace layout
    char* ws = (char*)d_ws;
    const size_t SZ_F32 = (size_t)NB * NS * ND * 4;    // 16 MB
    const size_t SZ_BF  = (size_t)NB * NS * ND * 2;    // 8 MB
    const size_t SZ_BD  = (size_t)NB * NH * NS * NS * 4; // 256 MB
    const size_t SZ_MID = (size_t)NB * NS * NDF * 2;   // 32 MB
    const size_t SZ_RBF = (size_t)NS * ND * 2;         // 1 MB
    const size_t SZ_W   = (size_t)ND * ND * 2;         // 512 KB
    const size_t SZ_W12 = (size_t)ND * NDF * 2;        // 2 MB
    const size_t needed = SZ_BD + 2 * SZ_F32 + 8 * SZ_BF + SZ_MID + 2 * SZ_RBF + 5 * SZ_W + 2 * SZ_W12;
    if (ws_size < needed) return;

    float* bdbuf = (float*)ws; ws += SZ_BD;
    float* tmp  = (float*)ws; ws += SZ_F32;
    float* h1   = (float*)ws; ws += SZ_F32;
    short* x_bf = (short*)ws; ws += SZ_BF;
    short* qu_bf = (short*)ws; ws += SZ_BF;
    short* qv_bf = (short*)ws; ws += SZ_BF;
    short* k_bf = (short*)ws; ws += SZ_BF;
    short* vbuf = (short*)ws; ws += SZ_BF;
    short* vT   = (short*)ws; ws += SZ_BF;
    short* ctx  = (short*)ws; ws += SZ_BF;
    short* h1b  = (short*)ws; ws += SZ_BF;
    short* mid  = (short*)ws; ws += SZ_MID;
    short* rel_bf = (short*)ws; ws += SZ_RBF;
    short* r_bf   = (short*)ws; ws += SZ_RBF;
    short* WqT = (short*)ws; ws += SZ_W;
    short* WkT = (short*)ws; ws += SZ_W;
    short* WvT = (short*)ws; ws += SZ_W;
    short* WrT = (short*)ws; ws += SZ_W;
    short* WoT = (short*)ws; ws += SZ_W;
    short* W1T = (short*)ws; ws += SZ_W12;   // (NDF, ND)
    short* W2T = (short*)ws; ws += SZ_W12;   // (ND, NDF)

    dim3 blk(256);
    const int M = NB * NS;

    // casts + weight transposes (bf16)
    cast_kernel<<<dim3((M * ND / 4 + 255) / 256), blk, 0, stream>>>((const float4*)x, x_bf, M * ND / 4);
    cast_kernel<<<dim3((NS * ND / 4 + 255) / 256), blk, 0, stream>>>((const float4*)rel, rel_bf, NS * ND / 4);
    transpose_cast_kernel<<<dim3(ND / 32, ND / 32), blk, 0, stream>>>(Wq, WqT, ND, ND);
    transpose_cast_kernel<<<dim3(ND / 32, ND / 32), blk, 0, stream>>>(Wk, WkT, ND, ND);
    transpose_cast_kernel<<<dim3(ND / 32, ND / 32), blk, 0, stream>>>(Wv, WvT, ND, ND);
    transpose_cast_kernel<<<dim3(ND / 32, ND / 32), blk, 0, stream>>>(Wr, WrT, ND, ND);
    transpose_cast_kernel<<<dim3(ND / 32, ND / 32), blk, 0, stream>>>(Wo, WoT, ND, ND);
    transpose_cast_kernel<<<dim3(NDF / 32, ND / 32), blk, 0, stream>>>(W1, W1T, ND, NDF);
    transpose_cast_kernel<<<dim3(ND / 32, NDF / 32), blk, 0, stream>>>(W2, W2T, NDF, ND);

    // projections (MFMA, bf16 outputs); Q has dual epilogue (qu = q+ub, qv = q+vb)
    mfma_gemm_kernel<bf16><<<dim3(ND / 128, M / 128), blk, 0, stream>>>(
        x_bf, WqT, ub, (bf16*)qu_bf, vb, qv_bf, M, ND, ND, 0);
    mfma_gemm_kernel<bf16><<<dim3(ND / 128, M / 128), blk, 0, stream>>>(
        x_bf, WkT, nullptr, (bf16*)k_bf, nullptr, nullptr, M, ND, ND, 0);
    mfma_gemm_kernel<bf16><<<dim3(ND / 128, M / 128), blk, 0, stream>>>(
        x_bf, WvT, nullptr, (bf16*)vbuf, nullptr, nullptr, M, ND, ND, 0);
    mfma_gemm_kernel<bf16><<<dim3(ND / 128, NS / 128), blk, 0, stream>>>(
        rel_bf, WrT, nullptr, (bf16*)r_bf, nullptr, nullptr, NS, ND, ND, 0);
    transpose_v_kernel<<<dim3(NS / 32, NDH / 32, NB * NH), blk, 0, stream>>>(vbuf, vT);

    // scores on MFMA: ac -> attn raw; bd -> bdbuf (q,u); softmax combines+shifts.
    score_mfma_kernel<0><<<dim3(NB * NH * 36), blk, 0, stream>>>(qu_bf, qv_bf, k_bf, r_bf, attn, bdbuf);
    score_mfma_kernel<1><<<dim3(NB * NH * 36), blk, 0, stream>>>(qu_bf, qv_bf, k_bf, r_bf, attn, bdbuf);
    softmax_kernel<<<dim3(NB * NH * NS / 4), blk, 0, stream>>>(attn, bdbuf);

    pv_mfma_kernel<<<dim3(NB * NH * (NS / 64)), blk, 0, stream>>>(attn, vT, ctx);

    // output proj + LN1 (h1 f32 + bf16 twin)
    mfma_gemm_kernel<float><<<dim3(ND / 128, M / 128), blk, 0, stream>>>(
        ctx, WoT, nullptr, tmp, nullptr, nullptr, M, ND, ND, 0);
    add_ln_kernel<<<dim3(M), blk, 0, stream>>>(x, tmp, g1, be1, h1, h1b);

    // FFN (MFMA) + LN2
    mfma_gemm_kernel<bf16><<<dim3(NDF / 128, M / 128), blk, 0, stream>>>(
        h1b, W1T, bb1, (bf16*)mid, nullptr, nullptr, M, NDF, ND, 1);
    mfma_gemm_kernel<float><<<dim3(ND / 128, M / 128), blk, 0, stream>>>(
        mid, W2T, bb2, tmp, nullptr, nullptr, M, ND, NDF, 0);
    add_ln_kernel<<<dim3(M), blk, 0, stream>>>(h1, tmp, g2, be2, out0, nullptr);
}